// Round 4
// baseline (270.177 us; speedup 1.0000x reference)
//
#include <hip/hip_runtime.h>
#include <math.h>

#define BB 8
#define CC 32
#define NTOK 241   // 4(q 2x2) + 121 + 64 + 36 + 16
#define NKV 237
#define YPADW 516
#define NBLK 256

// SMEM arena (floats), aliased across phases (grid barrier between phases).
// Pool phase: Ybuf = SMEM[0 .. 31*516)
// Attn phase offsets:
#define S_PL    0        // 32*241 = 7712
#define S_TOKS  7712     // 237*33 = 7821
#define S_KVLS  15533    // 237*65 = 15405
#define S_KVW   30938    // 2048
#define S_DW    32986    // 1152
#define S_DB    34138    // 128
#define S_QB    34266    // 32
#define S_KVB   34298    // 64
#define S_GLN   34362    // 32
#define S_BLN   34394    // 32
#define S_QTOK  34426    // 128
#define S_ATTNO 34554    // 132 -> end 34686
#define SMEM_F  34816    // 139,264 B

// ---------------------------------------------------------------------------
// device-scope grid barrier (256 co-resident blocks; state in d_ws, zeroed
// by a 16B hipMemsetAsync before each launch -> replay-safe, deterministic)
// ---------------------------------------------------------------------------
__device__ __forceinline__ void grid_barrier(unsigned* bar) {
  __syncthreads();
  if (threadIdx.x == 0) {
    __threadfence();
    unsigned old = __hip_atomic_fetch_add(&bar[0], 1u, __ATOMIC_ACQ_REL,
                                          __HIP_MEMORY_SCOPE_AGENT);
    if (old == (unsigned)NBLK - 1) {
      __hip_atomic_store(&bar[1], 1u, __ATOMIC_RELEASE,
                         __HIP_MEMORY_SCOPE_AGENT);
    } else {
      while (__hip_atomic_load(&bar[1], __ATOMIC_ACQUIRE,
                               __HIP_MEMORY_SCOPE_AGENT) == 0u)
        __builtin_amdgcn_s_sleep(32);
    }
    __threadfence();
  }
  __syncthreads();
}

// ---------------------------------------------------------------------------
// adaptive-pool window machine (full plane, lo=0, hi=512)
// ---------------------------------------------------------------------------
struct Win { int i, s, e; float acc; };

template <int P, int BASE>
__device__ __forceinline__ void wstep(Win& w, float v, int r, float* Y, int c) {
  w.acc += v;
  if (r == w.e - 1) {                       // block-uniform branch
    Y[(BASE + w.i) * YPADW + c] = w.acc * (1.0f / (float)(w.e - w.s));
    w.i++;
    int sn = (w.i * 512) / P;
    w.acc = (sn <= r) ? v : 0.0f;           // adjacent windows overlap <=1 row
    w.s = sn;
    w.e = ((w.i + 1) * 512 + P - 1) / P;
  }
}

__device__ __forceinline__ void load16(float (&buf)[16],
                                       const float* __restrict__ xp, int r0) {
#pragma unroll
  for (int u = 0; u < 16; ++u) buf[u] = xp[(size_t)(r0 + u) * 512];
}

__global__ __launch_bounds__(512) void lrsa_fused(
    const float* __restrict__ x,
    const float* __restrict__ q_w, const float* __restrict__ q_b,
    const float* __restrict__ kv_w, const float* __restrict__ kv_b,
    const float* __restrict__ proj_w, const float* __restrict__ proj_b,
    const float* __restrict__ norm_g, const float* __restrict__ norm_b,
    const float* __restrict__ dconv_w, const float* __restrict__ dconv_b,
    float* __restrict__ pooled, float* __restrict__ o_ws,
    unsigned* __restrict__ bars, float* __restrict__ out) {
  __shared__ float SMEM[SMEM_F];

  const int plane = blockIdx.x;             // b*32 + c
  const int tid = threadIdx.x;

  // ================= Phase 1: adaptive pooling (one plane/block) ==========
  {
    const int c = tid;                      // column 0..511
    const float* xp = x + (size_t)plane * (512 * 512) + c;
    Win L2v{0, 0, 256, 0.f};
    Win L11{0, 0, 47, 0.f};
    Win L8{0, 0, 64, 0.f};
    Win L6{0, 0, 86, 0.f};
    Win L4{0, 0, 128, 0.f};

    float A[16], B[16], Cb[16];
    load16(A, xp, 0);
    load16(B, xp, 16);
#define PROC16(BUF, R0)                                                        \
  _Pragma("unroll") for (int u = 0; u < 16; ++u) {                             \
    float v = BUF[u]; int r = (R0) + u;                                        \
    wstep<2, 0>(L2v, v, r, SMEM, c);                                           \
    wstep<11, 2>(L11, v, r, SMEM, c);                                          \
    wstep<8, 13>(L8, v, r, SMEM, c);                                           \
    wstep<6, 21>(L6, v, r, SMEM, c);                                           \
    wstep<4, 27>(L4, v, r, SMEM, c);                                           \
  }
    for (int rb = 0; rb < 480; rb += 48) {
      load16(Cb, xp, rb + 32);
      PROC16(A, rb);
      load16(A, xp, rb + 48);
      PROC16(B, rb + 16);
      load16(B, xp, rb + 64);
      PROC16(Cb, rb + 32);
    }
    PROC16(A, 480);
    PROC16(B, 496);
#undef PROC16
    __syncthreads();

    // W-pool the 31x512 intermediate into 241 tokens
    if (c < NTOK) {
      int k = c, p, kbase, kb;
      if (k < 4)        { p = 2;  kbase = 0;  kb = 0; }
      else if (k < 125) { p = 11; kbase = 2;  kb = 4; }
      else if (k < 189) { p = 8;  kbase = 13; kb = 125; }
      else if (k < 225) { p = 6;  kbase = 21; kb = 189; }
      else              { p = 4;  kbase = 27; kb = 225; }
      int idx = k - kb, i = idx / p, j = idx - i * p;
      int s = (j * 512) / p, e = ((j + 1) * 512 + p - 1) / p;
      const float* row = &SMEM[(kbase + i) * YPADW];
      float t0 = 0.f, t1 = 0.f, t2 = 0.f, t3 = 0.f;
      int cc = s;
      for (; cc + 4 <= e; cc += 4) {
        t0 += row[cc]; t1 += row[cc + 1]; t2 += row[cc + 2]; t3 += row[cc + 3];
      }
      for (; cc < e; ++cc) t0 += row[cc];
      pooled[(size_t)plane * NTOK + k] = ((t0 + t1) + (t2 + t3)) / (float)(e - s);
    }
  }

  grid_barrier(bars);                        // bars[0..1]

  // ================= Phase 2: token pipeline + attention (blocks 0..7) ====
  if (blockIdx.x < BB) {
    const int b = blockIdx.x;
    float* pl    = SMEM + S_PL;
    float* toks  = SMEM + S_TOKS;            // [t][33]
    float* kvls  = SMEM + S_KVLS;            // [t][65]
    float* kvw   = SMEM + S_KVW;
    float* dw    = SMEM + S_DW;
    float* dbias = SMEM + S_DB;
    float* qbias = SMEM + S_QB;
    float* kvb   = SMEM + S_KVB;
    float* gln   = SMEM + S_GLN;
    float* bln   = SMEM + S_BLN;
    float* qtok  = SMEM + S_QTOK;            // [4][32]
    float* attno = SMEM + S_ATTNO;           // [4][33]

    const float* plg = pooled + (size_t)b * CC * NTOK;
    for (int i = tid; i < CC * NTOK; i += 512) pl[i] = plg[i];
    for (int i = tid; i < CC * 64; i += 512) kvw[i] = kv_w[i];
    for (int i = tid; i < 4 * CC * 9; i += 512) dw[i] = dconv_w[i];
    if (tid < 4 * CC) dbias[tid] = dconv_b[tid];
    if (tid < CC) { qbias[tid] = q_b[tid]; gln[tid] = norm_g[tid]; bln[tid] = norm_b[tid]; }
    if (tid >= 64 && tid < 128) kvb[tid - 64] = kv_b[tid - 64];
    __syncthreads();

    // depthwise 3x3 conv (SAME, zero pad) + residual -> toks
    for (int item = tid; item < NKV * CC; item += 512) {
      int t = item >> 5, c = item & 31;
      int l, p, kb_, tb;
      if (t < 121)      { l = 0; p = 11; kb_ = 4;   tb = 0; }
      else if (t < 185) { l = 1; p = 8;  kb_ = 125; tb = 121; }
      else if (t < 221) { l = 2; p = 6;  kb_ = 189; tb = 185; }
      else              { l = 3; p = 4;  kb_ = 225; tb = 221; }
      int ti = t - tb;
      int i = ti / p, j = ti - i * p;
      const float* plc = pl + c * NTOK + kb_;
      const float* w9 = dw + (l * CC + c) * 9;
      float acc = dbias[l * CC + c];
#pragma unroll
      for (int dy = -1; dy <= 1; ++dy)
#pragma unroll
        for (int dx = -1; dx <= 1; ++dx) {
          int ii = i + dy, jj = j + dx;
          if (ii >= 0 && ii < p && jj >= 0 && jj < p)
            acc += w9[(dy + 1) * 3 + (dx + 1)] * plc[ii * p + jj];
        }
      toks[t * 33 + c] = plc[i * p + j] + acc;
    }
    __syncthreads();

    // LayerNorm over C (threads 0..236) ; q linear (threads 384..511)
    if (tid < NKV) {
      float xv[32]; float m = 0.f;
#pragma unroll
      for (int c = 0; c < 32; ++c) { xv[c] = toks[tid * 33 + c]; m += xv[c]; }
      m *= (1.0f / 32.0f);
      float v = 0.f;
#pragma unroll
      for (int c = 0; c < 32; ++c) { float d = xv[c] - m; v += d * d; }
      v *= (1.0f / 32.0f);
      float rs = rsqrtf(v + 1e-5f);
#pragma unroll
      for (int c = 0; c < 32; ++c)
        toks[tid * 33 + c] = (xv[c] - m) * rs * gln[c] + bln[c];
    } else if (tid >= 384) {
      int it = tid - 384;
      int n = it >> 5, u = it & 31;
      float acc = qbias[u];
#pragma unroll
      for (int c = 0; c < 32; ++c) acc += pl[c * NTOK + n] * q_w[c * 32 + u];
      qtok[n * 32 + u] = acc * 0.25f;        // fold scale = hd^-0.5
    }
    __syncthreads();

    // kv = toks_ln @ kv_w + kv_b   (237 x 64)
    for (int item = tid; item < NKV * 64; item += 512) {
      int t = item >> 6, u = item & 63;
      float acc = kvb[u];
#pragma unroll
      for (int c = 0; c < 32; ++c) acc += toks[t * 33 + c] * kvw[c * 64 + u];
      kvls[t * 65 + u] = acc;
    }
    __syncthreads();

    // attention: 8 waves <-> 8 (head, query) pairs
    {
      int wave = tid >> 6, lane = tid & 63;
      int h = wave >> 2, qi = wave & 3;
      float qv[16];
#pragma unroll
      for (int d = 0; d < 16; ++d) qv[d] = qtok[qi * 32 + h * 16 + d];
      float sc[4];
#pragma unroll
      for (int m = 0; m < 4; ++m) {
        int t = lane + m * 64;
        float s = -1e30f;
        if (t < NKV) {
          s = 0.f;
#pragma unroll
          for (int d = 0; d < 16; ++d) s += qv[d] * kvls[t * 65 + h * 16 + d];
        }
        sc[m] = s;
      }
      float mx = fmaxf(fmaxf(sc[0], sc[1]), fmaxf(sc[2], sc[3]));
#pragma unroll
      for (int d = 1; d < 64; d <<= 1) mx = fmaxf(mx, __shfl_xor(mx, d));
      float pr[4]; float ssum = 0.f;
#pragma unroll
      for (int m = 0; m < 4; ++m) {
        int t = lane + m * 64;
        pr[m] = (t < NKV) ? expf(sc[m] - mx) : 0.0f;
        ssum += pr[m];
      }
#pragma unroll
      for (int d = 1; d < 64; d <<= 1) ssum += __shfl_xor(ssum, d);
      float acc[16];
#pragma unroll
      for (int d = 0; d < 16; ++d) acc[d] = 0.f;
#pragma unroll
      for (int m = 0; m < 4; ++m) {
        int t = lane + m * 64;
        if (t < NKV) {
          float p = pr[m];
#pragma unroll
          for (int d = 0; d < 16; ++d) acc[d] += p * kvls[t * 65 + 32 + h * 16 + d];
        }
      }
#pragma unroll
      for (int d = 0; d < 16; ++d) {
#pragma unroll
        for (int s = 1; s < 64; s <<= 1) acc[d] += __shfl_xor(acc[d], s);
      }
      if (lane == 0) {
        float inv = 1.0f / ssum;
#pragma unroll
        for (int d = 0; d < 16; ++d) attno[qi * 33 + h * 16 + d] = acc[d] * inv;
      }
    }
    __syncthreads();

    // proj: (4 x 32) @ proj_w + proj_b -> o_ws[(b*32+u)*4 + n]
    if (tid < 128) {
      int n = tid >> 5, u = tid & 31;
      float acc = proj_b[u];
#pragma unroll
      for (int c = 0; c < 32; ++c) acc += attno[n * 33 + c] * proj_w[c * 32 + u];
      o_ws[((size_t)b * 32 + u) * 4 + n] = acc;
    }
  }

  grid_barrier(bars + 2);                    // bars[2..3]

  // ================= Phase 3: bilinear upsample (one plane/block) =========
  {
    const float o00 = o_ws[plane * 4 + 0];
    const float o01 = o_ws[plane * 4 + 1];
    const float o10 = o_ws[plane * 4 + 2];
    const float o11 = o_ws[plane * 4 + 3];
    const int sub = tid >> 7, col4 = tid & 127;

    float top[4], bot[4];
#pragma unroll
    for (int k = 0; k < 4; ++k) {
      float cx = (float)(4 * col4 + k) + 0.5f;
      float ww = cx * (1.0f / 256.0f) - 0.5f;
      ww = fminf(fmaxf(ww, 0.0f), 1.0f);
      top[k] = o00 + ww * (o01 - o00);
      bot[k] = o10 + ww * (o11 - o10);
    }
    float* outp = out + (size_t)plane * (512 * 512);
    for (int i = 0; i < 128; ++i) {
      int r = 4 * i + sub;
      float wh = ((float)r + 0.5f) * (1.0f / 256.0f) - 0.5f;
      wh = fminf(fmaxf(wh, 0.0f), 1.0f);
      float4 v;
      v.x = top[0] + wh * (bot[0] - top[0]);
      v.y = top[1] + wh * (bot[1] - top[1]);
      v.z = top[2] + wh * (bot[2] - top[2]);
      v.w = top[3] + wh * (bot[3] - top[3]);
      *(float4*)(outp + (size_t)r * 512 + 4 * col4) = v;
    }
  }
}

extern "C" void kernel_launch(void* const* d_in, const int* in_sizes, int n_in,
                              void* d_out, int out_size, void* d_ws, size_t ws_size,
                              hipStream_t stream) {
  const float* x       = (const float*)d_in[0];
  const float* q_w     = (const float*)d_in[1];
  const float* q_b     = (const float*)d_in[2];
  const float* kv_w    = (const float*)d_in[3];
  const float* kv_b    = (const float*)d_in[4];
  const float* proj_w  = (const float*)d_in[5];
  const float* proj_b  = (const float*)d_in[6];
  const float* norm_g  = (const float*)d_in[7];
  const float* norm_b  = (const float*)d_in[8];
  const float* dconv_w = (const float*)d_in[9];
  const float* dconv_b = (const float*)d_in[10];
  float* out = (float*)d_out;

  unsigned* bars = (unsigned*)d_ws;                       // 4 x u32
  float* pooled  = (float*)((char*)d_ws + 64);            // 256*241 floats
  float* o_ws    = pooled + (size_t)BB * CC * NTOK;       // 1024 floats

  hipMemsetAsync(d_ws, 0, 16, stream);                    // zero barrier state
  lrsa_fused<<<NBLK, 512, 0, stream>>>(x, q_w, q_b, kv_w, kv_b, proj_w, proj_b,
                                       norm_g, norm_b, dconv_w, dconv_b,
                                       pooled, o_ws, bars, out);
}

// Round 5
// 210.439 us; speedup vs baseline: 1.2839x; 1.2839x over previous
//
#include <hip/hip_runtime.h>
#include <math.h>

#define BB 8
#define CC 32
#define NTOK 241   // 4(q 2x2) + 121 + 64 + 36 + 16
#define NKV 237
#define YPADW 516
#define NSLOT 16   // max Y rows per block: p2:1 p11:6 p8:4 p6:3 p4:2

// ---------------------------------------------------------------------------
// Kernel A (v4): linear-stream adaptive pooling. 2 blocks per plane (512
// blocks, 2/CU). Each block float4-streams its row range (8-row bands) into
// LDS, then per-column window machines consume from LDS (conflict-free).
// Window ownership by start row; p11's straddler handled by a 24-row overlap
// read in block q0. Each token written exactly once (no atomics).
// ---------------------------------------------------------------------------
struct Win { int idx, s, e, left; float acc; };

template <int P, int SBASE>
__device__ __forceinline__ void wstep(Win& w, int nown, float v, int r,
                                      float* __restrict__ Y, int c) {
  if (w.left > 0) {                          // block-uniform
    w.acc += (r >= w.s) ? v : 0.0f;
    if (r == w.e - 1) {                      // block-uniform
      Y[(SBASE + (nown - w.left)) * YPADW + c] = w.acc;   // raw H-sum
      w.left--;
      w.idx++;
      int sn = (w.idx * 512) / P;
      w.acc = (sn <= r) ? v : 0.0f;          // adjacent windows overlap <=1 row
      w.s = sn;
      w.e = ((w.idx + 1) * 512 + P - 1) / P;
    }
  }
}

template <int P>
__device__ __forceinline__ void winit(Win& w, int i0, int n) {
  w.idx = i0;
  w.s = (i0 * 512) / P;
  w.e = ((i0 + 1) * 512 + P - 1) / P;
  w.left = n;
  w.acc = 0.0f;
}

__global__ __launch_bounds__(512) void pool_kernel(const float* __restrict__ x,
                                                   float* __restrict__ pooled) {
  __shared__ float sh[8 * 512];              // 16,384 B band buffer
  __shared__ float Ybuf[NSLOT * YPADW];      // 33,024 B

  const int plane = blockIdx.x >> 1;         // b*32 + c
  const int q = blockIdx.x & 1;
  const int tid = threadIdx.x;
  const int c = tid;

  // per-q level configs: levels {p2, p11, p8, p6, p4}
  const int lo = q ? 256 : 0;
  const int nb = q ? 32 : 35;                // bands of 8 rows (q0 reads 280)
  int i0_2, n_2, i0_11, n_11, i0_8, n_8, i0_6, n_6, i0_4, n_4;
  if (q == 0) {
    i0_2 = 0; n_2 = 1; i0_11 = 0; n_11 = 6; i0_8 = 0; n_8 = 4;
    i0_6 = 0; n_6 = 3; i0_4 = 0; n_4 = 2;
  } else {
    i0_2 = 1; n_2 = 1; i0_11 = 6; n_11 = 5; i0_8 = 4; n_8 = 4;
    i0_6 = 3; n_6 = 3; i0_4 = 2; n_4 = 2;
  }

  Win W2, W11, W8, W6, W4;
  winit<2>(W2, i0_2, n_2);
  winit<11>(W11, i0_11, n_11);
  winit<8>(W8, i0_8, n_8);
  winit<6>(W6, i0_6, n_6);
  winit<4>(W4, i0_4, n_4);

  const float* xp = x + (size_t)plane * (512 * 512);
  const int row0 = tid >> 7;                 // 0..3
  const int cg = (tid & 127) * 4;            // float4 col offset

  float4 r0 = *(const float4*)(xp + (size_t)(lo + row0) * 512 + cg);
  float4 r1 = *(const float4*)(xp + (size_t)(lo + row0 + 4) * 512 + cg);

  for (int band = 0; band < nb; ++band) {
    *(float4*)(sh + row0 * 512 + cg) = r0;
    *(float4*)(sh + (row0 + 4) * 512 + cg) = r1;
    __syncthreads();
    if (band + 1 < nb) {
      int rb = lo + (band + 1) * 8;
      r0 = *(const float4*)(xp + (size_t)(rb + row0) * 512 + cg);
      r1 = *(const float4*)(xp + (size_t)(rb + row0 + 4) * 512 + cg);
    }
#pragma unroll
    for (int rr = 0; rr < 8; ++rr) {
      float v = sh[rr * 512 + c];
      int r = lo + band * 8 + rr;
      wstep<2, 0>(W2, n_2, v, r, Ybuf, c);
      wstep<11, 1>(W11, n_11, v, r, Ybuf, c);
      wstep<8, 7>(W8, n_8, v, r, Ybuf, c);
      wstep<6, 11>(W6, n_6, v, r, Ybuf, c);
      wstep<4, 14>(W4, n_4, v, r, Ybuf, c);
    }
    __syncthreads();
  }

  // Phase 2: W-pool owned Y rows into tokens (each token written once).
  const int Ps[5]  = {2, 11, 8, 6, 4};
  const int KBs[5] = {0, 4, 125, 189, 225};
  const int SBs[5] = {0, 1, 7, 11, 14};
  const int i0s[5] = {i0_2, i0_11, i0_8, i0_6, i0_4};
  const int ns[5]  = {n_2, n_11, n_8, n_6, n_4};
  int cum[6]; cum[0] = 0;
#pragma unroll
  for (int l = 0; l < 5; ++l) cum[l + 1] = cum[l] + ns[l] * Ps[l];

  if (tid < cum[5]) {
    int l = 0;
    while (tid >= cum[l + 1]) ++l;
    int P = Ps[l];
    int rel = tid - cum[l];
    int li = rel / P, j = rel - li * P;
    int i = i0s[l] + li;
    int s = (i * 512) / P, e = ((i + 1) * 512 + P - 1) / P;
    int sw = (j * 512) / P, ew = ((j + 1) * 512 + P - 1) / P;
    const float* row = &Ybuf[(SBs[l] + li) * YPADW];
    float t0 = 0.f, t1 = 0.f, t2 = 0.f, t3 = 0.f;
    int cc = sw;
    for (; cc + 4 <= ew; cc += 4) {
      t0 += row[cc]; t1 += row[cc + 1]; t2 += row[cc + 2]; t3 += row[cc + 3];
    }
    for (; cc < ew; ++cc) t0 += row[cc];
    float val = ((t0 + t1) + (t2 + t3)) / (float)((e - s) * (ew - sw));
    pooled[(size_t)plane * NTOK + KBs[l] + i * P + j] = val;
  }
}

// ---------------------------------------------------------------------------
// Kernel B: token pipeline (dw-conv residual, LN, q/kv linears, attention,
// proj). One block per batch element.
// ---------------------------------------------------------------------------
__global__ __launch_bounds__(512) void attn_kernel(
    const float* __restrict__ pooled,
    const float* __restrict__ q_w, const float* __restrict__ q_b,
    const float* __restrict__ kv_w, const float* __restrict__ kv_b,
    const float* __restrict__ proj_w, const float* __restrict__ proj_b,
    const float* __restrict__ norm_g, const float* __restrict__ norm_b,
    const float* __restrict__ dconv_w, const float* __restrict__ dconv_b,
    float* __restrict__ o_out) {
  __shared__ float pl[CC * NTOK];
  __shared__ float toks[NKV][33];
  __shared__ float kvls[NKV][65];      // k: 0..31, v: 32..63
  __shared__ float kvw[CC * 64];
  __shared__ float dw[4 * CC * 9];
  __shared__ float dbias[4 * CC];
  __shared__ float qbias[CC], kvb[64], gln[CC], bln[CC];
  __shared__ float qtok[4][CC];
  __shared__ float attno[4][33];

  const int b = blockIdx.x, tid = threadIdx.x;
  const float* plg = pooled + (size_t)b * CC * NTOK;
  for (int i = tid; i < CC * NTOK; i += 512) pl[i] = plg[i];
  for (int i = tid; i < CC * 64; i += 512) kvw[i] = kv_w[i];
  for (int i = tid; i < 4 * CC * 9; i += 512) dw[i] = dconv_w[i];
  if (tid < 4 * CC) dbias[tid] = dconv_b[tid];
  if (tid < CC) { qbias[tid] = q_b[tid]; gln[tid] = norm_g[tid]; bln[tid] = norm_b[tid]; }
  if (tid >= 64 && tid < 128) kvb[tid - 64] = kv_b[tid - 64];
  __syncthreads();

  // depthwise 3x3 conv (SAME, zero pad) + residual -> toks
  for (int item = tid; item < NKV * CC; item += 512) {
    int t = item >> 5, c = item & 31;
    int l, p, kb_, tb;
    if (t < 121)      { l = 0; p = 11; kb_ = 4;   tb = 0; }
    else if (t < 185) { l = 1; p = 8;  kb_ = 125; tb = 121; }
    else if (t < 221) { l = 2; p = 6;  kb_ = 189; tb = 185; }
    else              { l = 3; p = 4;  kb_ = 225; tb = 221; }
    int ti = t - tb;
    int i = ti / p, j = ti - i * p;
    const float* plc = pl + c * NTOK + kb_;
    const float* w9 = dw + (l * CC + c) * 9;
    float acc = dbias[l * CC + c];
#pragma unroll
    for (int dy = -1; dy <= 1; ++dy)
#pragma unroll
      for (int dx = -1; dx <= 1; ++dx) {
        int ii = i + dy, jj = j + dx;
        if (ii >= 0 && ii < p && jj >= 0 && jj < p)
          acc += w9[(dy + 1) * 3 + (dx + 1)] * plc[ii * p + jj];
      }
    toks[t][c] = plc[i * p + j] + acc;
  }
  __syncthreads();

  // LayerNorm over C (threads 0..236) ; q linear (threads 384..511)
  if (tid < NKV) {
    float xv[32]; float m = 0.f;
#pragma unroll
    for (int c = 0; c < 32; ++c) { xv[c] = toks[tid][c]; m += xv[c]; }
    m *= (1.0f / 32.0f);
    float v = 0.f;
#pragma unroll
    for (int c = 0; c < 32; ++c) { float d = xv[c] - m; v += d * d; }
    v *= (1.0f / 32.0f);
    float rs = rsqrtf(v + 1e-5f);
#pragma unroll
    for (int c = 0; c < 32; ++c) toks[tid][c] = (xv[c] - m) * rs * gln[c] + bln[c];
  } else if (tid >= 384) {
    int it = tid - 384;
    int n = it >> 5, u = it & 31;
    float acc = qbias[u];
#pragma unroll
    for (int c = 0; c < 32; ++c) acc += pl[c * NTOK + n] * q_w[c * 32 + u];
    qtok[n][u] = acc * 0.25f;         // fold scale = hd^-0.5
  }
  __syncthreads();

  // kv = toks_ln @ kv_w + kv_b   (237 x 64)
  for (int item = tid; item < NKV * 64; item += 512) {
    int t = item >> 6, u = item & 63;
    float acc = kvb[u];
#pragma unroll
    for (int c = 0; c < 32; ++c) acc += toks[t][c] * kvw[c * 64 + u];
    kvls[t][u] = acc;
  }
  __syncthreads();

  // attention: 8 waves <-> 8 (head, query) pairs
  {
    int wave = tid >> 6, lane = tid & 63;
    int h = wave >> 2, qi = wave & 3;
    float qv[16];
#pragma unroll
    for (int d = 0; d < 16; ++d) qv[d] = qtok[qi][h * 16 + d];
    float sc[4];
#pragma unroll
    for (int m = 0; m < 4; ++m) {
      int t = lane + m * 64;
      float s = -1e30f;
      if (t < NKV) {
        s = 0.f;
#pragma unroll
        for (int d = 0; d < 16; ++d) s += qv[d] * kvls[t][h * 16 + d];
      }
      sc[m] = s;
    }
    float mx = fmaxf(fmaxf(sc[0], sc[1]), fmaxf(sc[2], sc[3]));
#pragma unroll
    for (int d = 1; d < 64; d <<= 1) mx = fmaxf(mx, __shfl_xor(mx, d));
    float pr[4]; float ssum = 0.f;
#pragma unroll
    for (int m = 0; m < 4; ++m) {
      int t = lane + m * 64;
      pr[m] = (t < NKV) ? expf(sc[m] - mx) : 0.0f;
      ssum += pr[m];
    }
#pragma unroll
    for (int d = 1; d < 64; d <<= 1) ssum += __shfl_xor(ssum, d);
    float acc[16];
#pragma unroll
    for (int d = 0; d < 16; ++d) acc[d] = 0.f;
#pragma unroll
    for (int m = 0; m < 4; ++m) {
      int t = lane + m * 64;
      if (t < NKV) {
        float p = pr[m];
#pragma unroll
        for (int d = 0; d < 16; ++d) acc[d] += p * kvls[t][32 + h * 16 + d];
      }
    }
#pragma unroll
    for (int d = 0; d < 16; ++d) {
#pragma unroll
      for (int s = 1; s < 64; s <<= 1) acc[d] += __shfl_xor(acc[d], s);
    }
    if (lane == 0) {
      float inv = 1.0f / ssum;
#pragma unroll
      for (int d = 0; d < 16; ++d) attno[qi][h * 16 + d] = acc[d] * inv;
    }
  }
  __syncthreads();

  // proj: (4 x 32) @ proj_w + proj_b -> o_out[(b*32+u)*4 + n]
  if (tid < 128) {
    int n = tid >> 5, u = tid & 31;
    float acc = proj_b[u];
#pragma unroll
    for (int c = 0; c < 32; ++c) acc += attno[n][c] * proj_w[c * 32 + u];
    o_out[((size_t)b * 32 + u) * 4 + n] = acc;
  }
}

// ---------------------------------------------------------------------------
// Kernel C: bilinear upsample 2x2 -> 512x512 (align_corners=False, clamped).
// ---------------------------------------------------------------------------
__global__ __launch_bounds__(256) void upsample_kernel(const float* __restrict__ o_in,
                                                       float* __restrict__ out) {
  const int plane = blockIdx.x >> 3;
  const int chunk = blockIdx.x & 7;
  const int tid = threadIdx.x;
  const int sub = tid >> 7, col4 = tid & 127;

  const float o00 = o_in[plane * 4 + 0];
  const float o01 = o_in[plane * 4 + 1];
  const float o10 = o_in[plane * 4 + 2];
  const float o11 = o_in[plane * 4 + 3];

  float top[4], bot[4];
#pragma unroll
  for (int k = 0; k < 4; ++k) {
    float c = (float)(4 * col4 + k) + 0.5f;
    float ww = c * (1.0f / 256.0f) - 0.5f;
    ww = fminf(fmaxf(ww, 0.0f), 1.0f);
    top[k] = o00 + ww * (o01 - o00);
    bot[k] = o10 + ww * (o11 - o10);
  }
  float* outp = out + (size_t)plane * (512 * 512);
  const int r0 = chunk * 64;
  for (int i = 0; i < 32; ++i) {
    int r = r0 + 2 * i + sub;
    float wh = ((float)r + 0.5f) * (1.0f / 256.0f) - 0.5f;
    wh = fminf(fmaxf(wh, 0.0f), 1.0f);
    float4 v;
    v.x = top[0] + wh * (bot[0] - top[0]);
    v.y = top[1] + wh * (bot[1] - top[1]);
    v.z = top[2] + wh * (bot[2] - top[2]);
    v.w = top[3] + wh * (bot[3] - top[3]);
    *(float4*)(outp + r * 512 + 4 * col4) = v;
  }
}

extern "C" void kernel_launch(void* const* d_in, const int* in_sizes, int n_in,
                              void* d_out, int out_size, void* d_ws, size_t ws_size,
                              hipStream_t stream) {
  const float* x       = (const float*)d_in[0];
  const float* q_w     = (const float*)d_in[1];
  const float* q_b     = (const float*)d_in[2];
  const float* kv_w    = (const float*)d_in[3];
  const float* kv_b    = (const float*)d_in[4];
  const float* proj_w  = (const float*)d_in[5];
  const float* proj_b  = (const float*)d_in[6];
  const float* norm_g  = (const float*)d_in[7];
  const float* norm_b  = (const float*)d_in[8];
  const float* dconv_w = (const float*)d_in[9];
  const float* dconv_b = (const float*)d_in[10];
  float* out = (float*)d_out;

  float* pooled = (float*)d_ws;                     // 256*241 floats
  float* o_ws   = pooled + (size_t)BB * CC * NTOK;  // 1024 floats

  pool_kernel<<<BB * CC * 2, 512, 0, stream>>>(x, pooled);
  attn_kernel<<<BB, 512, 0, stream>>>(pooled, q_w, q_b, kv_w, kv_b, proj_w,
                                      proj_b, norm_g, norm_b, dconv_w, dconv_b,
                                      o_ws);
  upsample_kernel<<<BB * CC * 8, 256, 0, stream>>>(o_ws, out);
}